// Round 8
// baseline (557.124 us; speedup 1.0000x reference)
//
#include <hip/hip_runtime.h>
#include <math.h>

typedef __bf16 bf16;
typedef __attribute__((ext_vector_type(8))) __bf16 bf16x8;
typedef __attribute__((ext_vector_type(4))) __bf16 bf16x4;
typedef __attribute__((ext_vector_type(4))) float floatx4;

#define MFMA(a, b, c) __builtin_amdgcn_mfma_f32_16x16x32_bf16((a), (b), (c), 0, 0, 0)

__device__ __forceinline__ void async_load16(const bf16* g, bf16* l) {
    __builtin_amdgcn_global_load_lds((const __attribute__((address_space(1))) void*)(g),
                                     (__attribute__((address_space(3))) void*)(l), 16, 0, 0);
}

// pack two floats to one dword of 2 bf16 (compiler emits v_cvt_pk_bf16_f32).
__device__ __forceinline__ unsigned pkbf16(float a, float b) {
    unsigned short ua = __builtin_bit_cast(unsigned short, (bf16)a);
    unsigned short ub = __builtin_bit_cast(unsigned short, (bf16)b);
    return ((unsigned)ub << 16) | (unsigned)ua;
}

// fast GELU (tanh form, exp2-based). |diff vs exact erf-gelu| <= ~3e-3.
__device__ __forceinline__ float gelu_fast(float t) {
    const float g  = 0.7978845608f * (t + 0.044715f * t * t * t);
    const float u  = __builtin_amdgcn_exp2f(g * 2.885390082f);  // e^{2g}
    const float th = (u - 1.0f) * __builtin_amdgcn_rcpf(u + 1.0f);
    return 0.5f * t * (1.0f + th);
}

// ---------------------------------------------------------------------------
// fp32 -> bf16 cast of all 4 weight matrices in one launch.
// ---------------------------------------------------------------------------
__global__ __launch_bounds__(256) void cast4_kernel(const float* __restrict__ a0,
                                                    const float* __restrict__ a1,
                                                    const float* __restrict__ a2,
                                                    const float* __restrict__ a3,
                                                    bf16* __restrict__ o0,
                                                    bf16* __restrict__ o1,
                                                    bf16* __restrict__ o2,
                                                    bf16* __restrict__ o3) {
    long i = (long)blockIdx.x * 256 + threadIdx.x;  // 8-elem units
    const float* in;
    bf16* out;
    long off;
    if (i < 393216) { in = a0; out = o0; off = i; }
    else if (i < 524288) { in = a1; out = o1; off = i - 393216; }
    else if (i < 1048576) { in = a2; out = o2; off = i - 524288; }
    else { in = a3; out = o3; off = i - 1048576; }
    const float4 a = ((const float4*)in)[2 * off];
    const float4 b = ((const float4*)in)[2 * off + 1];
    bf16x8 o;
    o[0] = (bf16)a.x; o[1] = (bf16)a.y; o[2] = (bf16)a.z; o[3] = (bf16)a.w;
    o[4] = (bf16)b.x; o[5] = (bf16)b.y; o[6] = (bf16)b.z; o[7] = (bf16)b.w;
    *(bf16x8*)(out + off * 8) = o;
}

// ---------------------------------------------------------------------------
// LayerNorm over 1024 cols, fp32 in -> bf16 out. One block (256 thr) per row.
// ---------------------------------------------------------------------------
__global__ __launch_bounds__(256) void ln_kernel(const float* __restrict__ x,
                                                 const float* __restrict__ g,
                                                 const float* __restrict__ b,
                                                 bf16* __restrict__ out) {
    const int row = blockIdx.x;
    const int tid = threadIdx.x;
    const float4 v = ((const float4*)(x + (long)row * 1024))[tid];
    float s  = v.x + v.y + v.z + v.w;
    float s2 = v.x * v.x + v.y * v.y + v.z * v.z + v.w * v.w;
#pragma unroll
    for (int off = 32; off > 0; off >>= 1) {
        s  += __shfl_xor(s, off, 64);
        s2 += __shfl_xor(s2, off, 64);
    }
    __shared__ float red[8];
    const int wave = tid >> 6, lane = tid & 63;
    if (lane == 0) { red[wave] = s; red[wave + 4] = s2; }
    __syncthreads();
    const float ts  = red[0] + red[1] + red[2] + red[3];
    const float ts2 = red[4] + red[5] + red[6] + red[7];
    const float mu   = ts * (1.0f / 1024.0f);
    const float rstd = rsqrtf(ts2 * (1.0f / 1024.0f) - mu * mu + 1e-5f);
    const float4 gg = ((const float4*)g)[tid];
    const float4 bb = ((const float4*)b)[tid];
    bf16x4 o;
    o[0] = (bf16)((v.x - mu) * rstd * gg.x + bb.x);
    o[1] = (bf16)((v.y - mu) * rstd * gg.y + bb.y);
    o[2] = (bf16)((v.z - mu) * rstd * gg.z + bb.z);
    o[3] = (bf16)((v.w - mu) * rstd * gg.w + bb.w);
    *(bf16x4*)(out + (long)row * 1024 + tid * 4) = o;
}

// ---------------------------------------------------------------------------
// 128x128-tile bf16 NT GEMM (m97 structure). Kept for N=1024 GEMMs (proj,
// fc2) where 256^2 tiles would launch only 128 blocks -> half the CUs idle.
// EPI: 1 = +bias+resid -> fp32 out.
// ---------------------------------------------------------------------------
template <int EPI>
__global__ __launch_bounds__(256, 4)
void gemm_bt(const bf16* __restrict__ A, const bf16* __restrict__ B,
             const float* __restrict__ bias, const float* __restrict__ resid,
             void* __restrict__ Cout, bf16* __restrict__ vtout, int M, int N, int K) {
    __shared__ __align__(16) bf16 sA[128 * 64];
    __shared__ __align__(16) bf16 sB[128 * 64];
    const int tid  = threadIdx.x;
    const int lane = tid & 63;
    const int wave = tid >> 6;
    const int wm = (wave >> 1) << 6;
    const int wn = (wave & 1) << 6;
    const int c15 = lane & 15;
    const int kq  = lane >> 4;
    const int c7  = lane & 7;
    const long tileM = (long)blockIdx.y * 128;
    const long tileN = (long)blockIdx.x * 128;

    floatx4 acc[4][4] = {};

    const int srow = tid >> 3;
    const int scol = ((tid & 7) ^ (srow & 7)) * 8;
    const bf16* Abase = A + (tileM + srow) * (long)K + scol;
    const bf16* Bbase = B + (tileN + srow) * (long)K + scol;
    bf16* sAw = sA + tid * 8;
    bf16* sBw = sB + tid * 8;

    for (int k0 = 0; k0 < K; k0 += 64) {
        __syncthreads();
#pragma unroll
        for (int it = 0; it < 4; ++it) {
            async_load16(Abase + (long)it * 32 * K + k0, sAw + it * 2048);
            async_load16(Bbase + (long)it * 32 * K + k0, sBw + it * 2048);
        }
        __syncthreads();
#pragma unroll
        for (int kk = 0; kk < 2; ++kk) {
            bf16x8 a[4], b[4];
#pragma unroll
            for (int i = 0; i < 4; ++i) {
                const int ch = ((kk << 2) + kq) ^ c7;
                a[i] = *(const bf16x8*)(sA + (wm + i * 16 + c15) * 64 + ch * 8);
                b[i] = *(const bf16x8*)(sB + (wn + i * 16 + c15) * 64 + ch * 8);
            }
#pragma unroll
            for (int i = 0; i < 4; ++i)
#pragma unroll
                for (int j = 0; j < 4; ++j)
                    acc[i][j] = MFMA(a[i], b[j], acc[i][j]);
        }
    }

#pragma unroll
    for (int i = 0; i < 4; ++i)
#pragma unroll
        for (int j = 0; j < 4; ++j) {
#pragma unroll
            for (int r = 0; r < 4; ++r) {
                const long gm = tileM + wm + i * 16 + kq * 4 + r;
                const long gn = tileN + wn + j * 16 + c15;
                const float v = acc[i][j][r];
                if (EPI == 0) {
                    ((bf16*)Cout)[gm * N + gn] = (bf16)v;
                } else if (EPI == 1) {
                    ((float*)Cout)[gm * N + gn] = v + bias[gn] + resid[gm * N + gn];
                } else {
                    ((bf16*)Cout)[gm * N + gn] = (bf16)gelu_fast(v + bias[gn]);
                }
            }
        }
}

// ---------------------------------------------------------------------------
// 256x256-tile bf16 NT GEMM, 8-phase schedule (T3+T4+T5), pinned skeleton.
// Measured R1/R2: ~parity with gemm_bt at K=1024 shapes. Kept for qkv/fc1.
// EPI: 2 = +bias,GELU -> bf16; 3 = qkv: Q/K bf16, V (n>=2048) transposed.
// ---------------------------------------------------------------------------
template <int EPI>
__global__ __launch_bounds__(512, 2)
void gemm_bt256(const bf16* __restrict__ A, const bf16* __restrict__ B,
                const float* __restrict__ bias, const float* __restrict__ resid,
                void* __restrict__ Cout, bf16* __restrict__ vtout,
                int M, int N, int K) {
    __shared__ __align__(16) bf16 s[4][2][8192];  // [H: A0,A1,B0,B1][buf][128x64]
    const int tid  = threadIdx.x;
    const int lane = tid & 63;
    const int wave = tid >> 6;
    const int c15 = lane & 15;
    const int kq  = lane >> 4;
    const int c7  = lane & 7;
    const int hA   = wave >> 2;          // which A half this wave reads
    const int hB   = (wave >> 1) & 1;    // which B half
    const int wsub = (wave & 1) << 6;    // col offset within B half
    const int wm = hA << 7;
    const int wn = (hB << 7) | wsub;
    const long tileM = (long)blockIdx.y * 256;
    const long tileN = (long)blockIdx.x * 256;
    const int nk = K >> 6;

    floatx4 acc[8][4] = {};

    const int srow = tid >> 3;                       // 0..63
    const int scol = ((tid & 7) ^ (srow & 7)) << 3;
    const bf16* ga0 = A + (tileM + srow) * (long)K + scol;
    const bf16* ga1 = ga0 + 128 * (long)K;
    const bf16* gb0 = B + (tileN + srow) * (long)K + scol;
    const bf16* gb1 = gb0 + 128 * (long)K;

#define STAGE(H, GP, kt)                                          \
    do {                                                          \
        if ((kt) < nk) {                                          \
            const bf16* _g = (GP) + ((long)(kt) << 6);            \
            bf16* _d = &s[H][(kt) & 1][tid * 8];                  \
            async_load16(_g, _d);                                 \
            async_load16(_g + 64 * (long)K, _d + 4096);           \
        }                                                         \
    } while (0)

// phase skeleton pins
#define PH_OPEN()                                                  \
    __builtin_amdgcn_sched_barrier(0);                             \
    __builtin_amdgcn_s_barrier();                                  \
    asm volatile("s_waitcnt lgkmcnt(0)" ::: "memory");             \
    __builtin_amdgcn_sched_barrier(0);                             \
    __builtin_amdgcn_s_setprio(1)

#define PH_CLOSE()                                                 \
    __builtin_amdgcn_s_setprio(0);                                 \
    __builtin_amdgcn_sched_barrier(0);                             \
    __builtin_amdgcn_s_barrier();                                  \
    __builtin_amdgcn_sched_barrier(0)

    // prologue: B0(0) B1(0) A0(0) A1(0) B0(1) B1(1); vmcnt(4) -> tile0 ready
    STAGE(2, gb0, 0); STAGE(3, gb1, 0);
    STAGE(0, ga0, 0); STAGE(1, ga1, 0);
    STAGE(2, gb0, 1); STAGE(3, gb1, 1);
    asm volatile("s_waitcnt vmcnt(4)" ::: "memory");
    __builtin_amdgcn_s_barrier();
    __builtin_amdgcn_sched_barrier(0);

    bf16x8 af[4][2], bL[2][2], bH[2][2];

#define RD(P, r, ks) \
    (*(const bf16x8*)((P) + ((r) << 6) + (((((ks) << 2) | kq) ^ c7) << 3)))

    for (int t = 0; t < nk; ++t) {
        const bf16* pa = s[hA][t & 1];
        const bf16* pb = s[2 + hB][t & 1];

        // ---- phase 1: quad (0,0) -------------------------------------
#pragma unroll
        for (int i = 0; i < 4; ++i) {
            af[i][0] = RD(pa, i * 16 + c15, 0);
            af[i][1] = RD(pa, i * 16 + c15, 1);
        }
#pragma unroll
        for (int j = 0; j < 2; ++j) {
            bL[j][0] = RD(pb, wsub + j * 16 + c15, 0);
            bL[j][1] = RD(pb, wsub + j * 16 + c15, 1);
        }
        STAGE(0, ga0, t + 1);
        PH_OPEN();
#pragma unroll
        for (int i = 0; i < 4; ++i)
#pragma unroll
            for (int j = 0; j < 2; ++j) {
                acc[i][j] = MFMA(af[i][0], bL[j][0], acc[i][j]);
                acc[i][j] = MFMA(af[i][1], bL[j][1], acc[i][j]);
            }
        PH_CLOSE();

        // ---- phase 2: quad (0,1) -------------------------------------
#pragma unroll
        for (int j = 0; j < 2; ++j) {
            bH[j][0] = RD(pb, wsub + 32 + j * 16 + c15, 0);
            bH[j][1] = RD(pb, wsub + 32 + j * 16 + c15, 1);
        }
        STAGE(1, ga1, t + 1);
        PH_OPEN();
#pragma unroll
        for (int i = 0; i < 4; ++i)
#pragma unroll
            for (int j = 0; j < 2; ++j) {
                acc[i][2 + j] = MFMA(af[i][0], bH[j][0], acc[i][2 + j]);
                acc[i][2 + j] = MFMA(af[i][1], bH[j][1], acc[i][2 + j]);
            }
        PH_CLOSE();

        // ---- phase 3: quad (1,1) -------------------------------------
#pragma unroll
        for (int i = 0; i < 4; ++i) {
            af[i][0] = RD(pa, 64 + i * 16 + c15, 0);
            af[i][1] = RD(pa, 64 + i * 16 + c15, 1);
        }
        STAGE(2, gb0, t + 2);
        PH_OPEN();
#pragma unroll
        for (int i = 0; i < 4; ++i)
#pragma unroll
            for (int j = 0; j < 2; ++j) {
                acc[4 + i][2 + j] = MFMA(af[i][0], bH[j][0], acc[4 + i][2 + j]);
                acc[4 + i][2 + j] = MFMA(af[i][1], bH[j][1], acc[4 + i][2 + j]);
            }
        PH_CLOSE();

        // ---- phase 4: quad (1,0), counted vmcnt at K-tile boundary ----
        STAGE(3, gb1, t + 2);
        __builtin_amdgcn_sched_barrier(0);
        __builtin_amdgcn_s_barrier();
        asm volatile("s_waitcnt lgkmcnt(0)" ::: "memory");
        __builtin_amdgcn_sched_barrier(0);
        __builtin_amdgcn_s_setprio(1);
#pragma unroll
        for (int i = 0; i < 4; ++i)
#pragma unroll
            for (int j = 0; j < 2; ++j) {
                acc[4 + i][j] = MFMA(af[i][0], bL[j][0], acc[4 + i][j]);
                acc[4 + i][j] = MFMA(af[i][1], bL[j][1], acc[4 + i][j]);
            }
        __builtin_amdgcn_s_setprio(0);
        __builtin_amdgcn_sched_barrier(0);
        asm volatile("s_waitcnt vmcnt(4)" ::: "memory");
        __builtin_amdgcn_s_barrier();
        __builtin_amdgcn_sched_barrier(0);
    }
#undef STAGE
#undef RD
#undef PH_OPEN
#undef PH_CLOSE

    // epilogue
#pragma unroll
    for (int i = 0; i < 8; ++i)
#pragma unroll
        for (int j = 0; j < 4; ++j) {
            if (EPI == 3 && tileN >= 2048) {
                // V: transposed store. Lane holds 4 consecutive tokens.
                const long gnv  = tileN - 2048 + wn + j * 16 + c15;
                const long tokb = tileM + wm + i * 16 + kq * 4;
                const long row  = ((tokb >> 11) << 10) + gnv;
                bf16x4 ov;
#pragma unroll
                for (int r = 0; r < 4; ++r) ov[r] = (bf16)acc[i][j][r];
                *(bf16x4*)(vtout + row * 2048 + (tokb & 2047)) = ov;
            } else {
#pragma unroll
                for (int r = 0; r < 4; ++r) {
                    const long gm = tileM + wm + i * 16 + kq * 4 + r;
                    const long gn = tileN + wn + j * 16 + c15;
                    const float v = acc[i][j][r];
                    if (EPI == 0 || EPI == 3) {
                        ((bf16*)Cout)[gm * N + gn] = (bf16)v;
                    } else if (EPI == 1) {
                        ((float*)Cout)[gm * N + gn] = v + bias[gn] + resid[gm * N + gn];
                    } else {
                        ((bf16*)Cout)[gm * N + gn] = (bf16)gelu_fast(v + bias[gn]);
                    }
                }
            }
        }
}

// ---------------------------------------------------------------------------
// Flash attention v8 = R7 permlane structure (bank conflicts 0, LDS 16KB) at
// 128 q-rows/block. R7 was grid-limited to 2 blocks/CU (Occupancy 20%);
// with sP gone, halving the q-block is cheap on LDS (K-frag total ~4MB/CU)
// and VGPR drops to ~100 (<=128 cliff) -> grid 64x16 = 1024 blocks =
// 4 blocks/CU = 4 waves/SIMD. Double the independent S->exp2->pack->PV
// chains per SIMD; exp2 (quarter-rate) hides under other waves' MFMA (m114).
// NO min-waves hint >2 (R5/R6: clamps VGPR to 64 and serializes).
// ---------------------------------------------------------------------------
__global__ __launch_bounds__(256, 2)
void attn_kernel(const bf16* __restrict__ qkv, const bf16* __restrict__ vt,
                 bf16* __restrict__ o) {
    __shared__ __align__(16) bf16 sK[2][64 * 64];
    const int bh = blockIdx.x, b = bh >> 4, h = bh & 15;
    const int q0 = blockIdx.y * 128;
    const int tid = threadIdx.x, lane = tid & 63, wave = tid >> 6;  // wave 0..3
    const int c15 = lane & 15, kq = lane >> 4, c7 = lane & 7;
    const int ch = ((kq & 1) << 1) | (kq >> 1);   // k-slot permutation

    // Q fragments: 2 q-tiles of 16 rows per wave; pre-scaled by log2(e)/8
    bf16x8 qf[2][2];
#pragma unroll
    for (int t = 0; t < 2; ++t) {
        const bf16* qrow =
            qkv + ((long)(b * 2048 + q0 + wave * 32 + t * 16 + c15)) * 3072 + h * 64;
#pragma unroll
        for (int kk = 0; kk < 2; ++kk) {
            const bf16x8 raw = *(const bf16x8*)(qrow + kk * 32 + kq * 8);
            bf16x8 sc;
#pragma unroll
            for (int e = 0; e < 8; ++e) sc[e] = (bf16)((float)raw[e] * 0.18033688f);
            qf[t][kk] = sc;
        }
    }

    floatx4 oacc[2][4] = {};
    float l_s[2] = {0.f, 0.f};

    const bf16* kbase = qkv + ((long)b * 2048) * 3072 + 1024 + h * 64;
    const bf16* vbase = vt + (long)bh * 64 * 2048;

    const int srow = tid >> 3;                       // 0..31
    const int scol = ((tid & 7) ^ (srow & 7)) * 8;

    // prologue: stage K tile 0 into buf 0
    async_load16(kbase + (long)srow * 3072 + scol, &sK[0][tid * 8]);
    async_load16(kbase + (long)(32 + srow) * 3072 + scol, &sK[0][tid * 8 + 2048]);
    __syncthreads();

    union U8 { unsigned u[4]; bf16x8 v; };

    for (int it = 0; it < 32; ++it) {
        const int kv0 = it << 6;
        const int cur = it & 1;
        // stage next K tile into other buffer (hidden under this iter's compute)
        if (it + 1 < 32) {
            async_load16(kbase + (long)(kv0 + 64 + srow) * 3072 + scol,
                         &sK[cur ^ 1][tid * 8]);
            async_load16(kbase + (long)(kv0 + 96 + srow) * 3072 + scol,
                         &sK[cur ^ 1][tid * 8 + 2048]);
        }

        // V^T fragments straight from global (L2-resident), issued EARLY so
        // the latency hides under the S phase. Address uses the CH k-slot
        // permutation to match pf.
        bf16x8 vf[4][2];
#pragma unroll
        for (int i = 0; i < 4; ++i) {
            const bf16* vrow = vbase + (long)(i * 16 + c15) * 2048 + kv0 + ch * 8;
            vf[i][0] = *(const bf16x8*)(vrow);
            vf[i][1] = *(const bf16x8*)(vrow + 32);
        }

        // S phase: per q-tile MFMA, exp2, pack to bf16 pairs (in-register)
        unsigned qp[2][8];
        {
            const bf16* sKr = sK[cur];
            bf16x8 kf[4][2];
#pragma unroll
            for (int j = 0; j < 4; ++j) {
                kf[j][0] = *(const bf16x8*)(sKr + (j * 16 + c15) * 64 + ((kq ^ c7) * 8));
                kf[j][1] = *(const bf16x8*)(sKr + (j * 16 + c15) * 64 + (((4 | kq) ^ c7) * 8));
            }
#pragma unroll
            for (int t = 0; t < 2; ++t) {
                floatx4 sv[4];
#pragma unroll
                for (int j = 0; j < 4; ++j) {
                    floatx4 a = {0.f, 0.f, 0.f, 0.f};
                    a = MFMA(kf[j][0], qf[t][0], a);
                    a = MFMA(kf[j][1], qf[t][1], a);
                    sv[j] = a;
                }
                float rs = 0.f;
#pragma unroll
                for (int j = 0; j < 4; ++j) {
                    const float p0 = __builtin_amdgcn_exp2f(sv[j][0]);
                    const float p1 = __builtin_amdgcn_exp2f(sv[j][1]);
                    const float p2 = __builtin_amdgcn_exp2f(sv[j][2]);
                    const float p3 = __builtin_amdgcn_exp2f(sv[j][3]);
                    rs += (p0 + p1) + (p2 + p3);
                    qp[t][2 * j]     = pkbf16(p0, p1);
                    qp[t][2 * j + 1] = pkbf16(p2, p3);
                }
                l_s[t] += rs;
            }
        }

        // P redistribution in-register: one permlane16_swap per dword pair.
        // (w0,w2)=swap(q0,q2); (w1,w3)=swap(q1,q3)  [pf0: kv 0..31]
        // (w0,w2)=swap(q4,q6); (w1,w3)=swap(q5,q7)  [pf1: kv 32..63]
#pragma unroll
        for (int t = 0; t < 2; ++t) {
            unsigned a0 = qp[t][0], b0 = qp[t][2];
            unsigned a1 = qp[t][1], b1 = qp[t][3];
            asm("v_permlane16_swap_b32 %0, %1" : "+v"(a0), "+v"(b0));
            asm("v_permlane16_swap_b32 %0, %1" : "+v"(a1), "+v"(b1));
            unsigned a2 = qp[t][4], b2 = qp[t][6];
            unsigned a3 = qp[t][5], b3 = qp[t][7];
            asm("v_permlane16_swap_b32 %0, %1" : "+v"(a2), "+v"(b2));
            asm("v_permlane16_swap_b32 %0, %1" : "+v"(a3), "+v"(b3));
            U8 x0; x0.u[0] = a0; x0.u[1] = a1; x0.u[2] = b0; x0.u[3] = b1;
            U8 x1; x1.u[0] = a2; x1.u[1] = a3; x1.u[2] = b2; x1.u[3] = b3;
            const bf16x8 pf0 = x0.v;
            const bf16x8 pf1 = x1.v;
#pragma unroll
            for (int i = 0; i < 4; ++i) {
                oacc[t][i] = MFMA(vf[i][0], pf0, oacc[t][i]);
                oacc[t][i] = MFMA(vf[i][1], pf1, oacc[t][i]);
            }
        }

        __syncthreads();  // drains stage (hidden) + protects sK[cur] reuse
    }

    // final cross-lane denom reduction + O write
#pragma unroll
    for (int t = 0; t < 2; ++t) {
        float rs = l_s[t];
        rs += __shfl_xor(rs, 16, 64);
        rs += __shfl_xor(rs, 32, 64);
        const float linv = 1.0f / rs;
        const long tok = (long)(b * 2048 + q0 + wave * 32 + t * 16 + c15);
#pragma unroll
        for (int i = 0; i < 4; ++i) {
            bf16x4 ov;
#pragma unroll
            for (int r = 0; r < 4; ++r) ov[r] = (bf16)(oacc[t][i][r] * linv);
            *(bf16x4*)(o + tok * 1024 + h * 64 + i * 16 + kq * 4) = ov;
        }
    }
}

// ---------------------------------------------------------------------------
extern "C" void kernel_launch(void* const* d_in, const int* in_sizes, int n_in,
                              void* d_out, int out_size, void* d_ws, size_t ws_size,
                              hipStream_t stream) {
    const float* x      = (const float*)d_in[0];
    const float* ln1_g  = (const float*)d_in[1];
    const float* ln1_b  = (const float*)d_in[2];
    const float* qkv_w  = (const float*)d_in[3];
    const float* proj_w = (const float*)d_in[4];
    const float* proj_b = (const float*)d_in[5];
    const float* ln2_g  = (const float*)d_in[6];
    const float* ln2_b  = (const float*)d_in[7];
    const float* fc1_w  = (const float*)d_in[8];
    const float* fc1_b  = (const float*)d_in[9];
    const float* fc2_w  = (const float*)d_in[10];
    const float* fc2_b  = (const float*)d_in[11];
    float* out = (float*)d_out;

    char* ws = (char*)d_ws;
    bf16* actbuf = (bf16*)(ws);                            // 16 MiB (h / o / h2)
    bf16* wqkv   = (bf16*)(ws + (16ull << 20));            // 6 MiB
    bf16* wproj  = (bf16*)(ws + (22ull << 20));            // 2 MiB
    bf16* wfc1   = (bf16*)(ws + (24ull << 20));            // 8 MiB
    bf16* wfc2   = (bf16*)(ws + (32ull << 20));            // 8 MiB
    bf16* qkvbuf = (bf16*)(ws + (40ull << 20));            // 48 MiB (V region unused)
    bf16* vtbuf  = (bf16*)(ws + (88ull << 20));            // 16 MiB
    bf16* gbuf   = (bf16*)(ws + (40ull << 20));            // 64 MiB (aliases qkv+vt)

    const dim3 blk(256);
    const dim3 blk512(512);

    cast4_kernel<<<6144, blk, 0, stream>>>(qkv_w, proj_w, fc1_w, fc2_w,
                                           wqkv, wproj, wfc1, wfc2);

    ln_kernel<<<8192, blk, 0, stream>>>(x, ln1_g, ln1_b, actbuf);

    gemm_bt256<3><<<dim3(12, 32), blk512, 0, stream>>>(actbuf, wqkv, nullptr, nullptr,
                                                       qkvbuf, vtbuf, 8192, 3072, 1024);
    attn_kernel<<<dim3(64, 16), blk, 0, stream>>>(qkvbuf, vtbuf, actbuf);

    gemm_bt<1><<<dim3(8, 64), blk, 0, stream>>>(actbuf, wproj, proj_b, x,
                                                d_out, nullptr, 8192, 1024, 1024);

    ln_kernel<<<8192, blk, 0, stream>>>(out, ln2_g, ln2_b, actbuf);

    gemm_bt256<2><<<dim3(16, 32), blk512, 0, stream>>>(actbuf, wfc1, fc1_b, nullptr,
                                                       gbuf, nullptr, 8192, 4096, 1024);
    gemm_bt<1><<<dim3(8, 64), blk, 0, stream>>>(gbuf, wfc2, fc2_b, out,
                                                d_out, nullptr, 8192, 1024, 4096);
}

// Round 9
// 528.004 us; speedup vs baseline: 1.0552x; 1.0552x over previous
//
#include <hip/hip_runtime.h>
#include <math.h>

typedef __bf16 bf16;
typedef __attribute__((ext_vector_type(8))) __bf16 bf16x8;
typedef __attribute__((ext_vector_type(4))) __bf16 bf16x4;
typedef __attribute__((ext_vector_type(4))) float floatx4;

#define MFMA(a, b, c) __builtin_amdgcn_mfma_f32_16x16x32_bf16((a), (b), (c), 0, 0, 0)

__device__ __forceinline__ void async_load16(const bf16* g, bf16* l) {
    __builtin_amdgcn_global_load_lds((const __attribute__((address_space(1))) void*)(g),
                                     (__attribute__((address_space(3))) void*)(l), 16, 0, 0);
}

// fast GELU (tanh form, exp2-based). |diff vs exact erf-gelu| <= ~3e-3.
__device__ __forceinline__ float gelu_fast(float t) {
    const float g  = 0.7978845608f * (t + 0.044715f * t * t * t);
    const float u  = __builtin_amdgcn_exp2f(g * 2.885390082f);  // e^{2g}
    const float th = (u - 1.0f) * __builtin_amdgcn_rcpf(u + 1.0f);
    return 0.5f * t * (1.0f + th);
}

// ---------------------------------------------------------------------------
// fp32 -> bf16 cast of all 4 weight matrices in one launch.
// ---------------------------------------------------------------------------
__global__ __launch_bounds__(256) void cast4_kernel(const float* __restrict__ a0,
                                                    const float* __restrict__ a1,
                                                    const float* __restrict__ a2,
                                                    const float* __restrict__ a3,
                                                    bf16* __restrict__ o0,
                                                    bf16* __restrict__ o1,
                                                    bf16* __restrict__ o2,
                                                    bf16* __restrict__ o3) {
    long i = (long)blockIdx.x * 256 + threadIdx.x;  // 8-elem units
    const float* in;
    bf16* out;
    long off;
    if (i < 393216) { in = a0; out = o0; off = i; }
    else if (i < 524288) { in = a1; out = o1; off = i - 393216; }
    else if (i < 1048576) { in = a2; out = o2; off = i - 524288; }
    else { in = a3; out = o3; off = i - 1048576; }
    const float4 a = ((const float4*)in)[2 * off];
    const float4 b = ((const float4*)in)[2 * off + 1];
    bf16x8 o;
    o[0] = (bf16)a.x; o[1] = (bf16)a.y; o[2] = (bf16)a.z; o[3] = (bf16)a.w;
    o[4] = (bf16)b.x; o[5] = (bf16)b.y; o[6] = (bf16)b.z; o[7] = (bf16)b.w;
    *(bf16x8*)(out + off * 8) = o;
}

// ---------------------------------------------------------------------------
// LayerNorm over 1024 cols, fp32 in -> bf16 out. One block (256 thr) per row.
// ---------------------------------------------------------------------------
__global__ __launch_bounds__(256) void ln_kernel(const float* __restrict__ x,
                                                 const float* __restrict__ g,
                                                 const float* __restrict__ b,
                                                 bf16* __restrict__ out) {
    const int row = blockIdx.x;
    const int tid = threadIdx.x;
    const float4 v = ((const float4*)(x + (long)row * 1024))[tid];
    float s  = v.x + v.y + v.z + v.w;
    float s2 = v.x * v.x + v.y * v.y + v.z * v.z + v.w * v.w;
#pragma unroll
    for (int off = 32; off > 0; off >>= 1) {
        s  += __shfl_xor(s, off, 64);
        s2 += __shfl_xor(s2, off, 64);
    }
    __shared__ float red[8];
    const int wave = tid >> 6, lane = tid & 63;
    if (lane == 0) { red[wave] = s; red[wave + 4] = s2; }
    __syncthreads();
    const float ts  = red[0] + red[1] + red[2] + red[3];
    const float ts2 = red[4] + red[5] + red[6] + red[7];
    const float mu   = ts * (1.0f / 1024.0f);
    const float rstd = rsqrtf(ts2 * (1.0f / 1024.0f) - mu * mu + 1e-5f);
    const float4 gg = ((const float4*)g)[tid];
    const float4 bb = ((const float4*)b)[tid];
    bf16x4 o;
    o[0] = (bf16)((v.x - mu) * rstd * gg.x + bb.x);
    o[1] = (bf16)((v.y - mu) * rstd * gg.y + bb.y);
    o[2] = (bf16)((v.z - mu) * rstd * gg.z + bb.z);
    o[3] = (bf16)((v.w - mu) * rstd * gg.w + bb.w);
    *(bf16x4*)(out + (long)row * 1024 + tid * 4) = o;
}

// ---------------------------------------------------------------------------
// 128x128-tile bf16 NT GEMM (m97 structure). Kept for N=1024 GEMMs (proj,
// fc2) where 256^2 tiles would launch only 128 blocks -> half the CUs idle.
// EPI: 1 = +bias+resid -> fp32 out.
// ---------------------------------------------------------------------------
template <int EPI>
__global__ __launch_bounds__(256, 4)
void gemm_bt(const bf16* __restrict__ A, const bf16* __restrict__ B,
             const float* __restrict__ bias, const float* __restrict__ resid,
             void* __restrict__ Cout, bf16* __restrict__ vtout, int M, int N, int K) {
    __shared__ __align__(16) bf16 sA[128 * 64];
    __shared__ __align__(16) bf16 sB[128 * 64];
    const int tid  = threadIdx.x;
    const int lane = tid & 63;
    const int wave = tid >> 6;
    const int wm = (wave >> 1) << 6;
    const int wn = (wave & 1) << 6;
    const int c15 = lane & 15;
    const int kq  = lane >> 4;
    const int c7  = lane & 7;
    const long tileM = (long)blockIdx.y * 128;
    const long tileN = (long)blockIdx.x * 128;

    floatx4 acc[4][4] = {};

    const int srow = tid >> 3;
    const int scol = ((tid & 7) ^ (srow & 7)) * 8;
    const bf16* Abase = A + (tileM + srow) * (long)K + scol;
    const bf16* Bbase = B + (tileN + srow) * (long)K + scol;
    bf16* sAw = sA + tid * 8;
    bf16* sBw = sB + tid * 8;

    for (int k0 = 0; k0 < K; k0 += 64) {
        __syncthreads();
#pragma unroll
        for (int it = 0; it < 4; ++it) {
            async_load16(Abase + (long)it * 32 * K + k0, sAw + it * 2048);
            async_load16(Bbase + (long)it * 32 * K + k0, sBw + it * 2048);
        }
        __syncthreads();
#pragma unroll
        for (int kk = 0; kk < 2; ++kk) {
            bf16x8 a[4], b[4];
#pragma unroll
            for (int i = 0; i < 4; ++i) {
                const int ch = ((kk << 2) + kq) ^ c7;
                a[i] = *(const bf16x8*)(sA + (wm + i * 16 + c15) * 64 + ch * 8);
                b[i] = *(const bf16x8*)(sB + (wn + i * 16 + c15) * 64 + ch * 8);
            }
#pragma unroll
            for (int i = 0; i < 4; ++i)
#pragma unroll
                for (int j = 0; j < 4; ++j)
                    acc[i][j] = MFMA(a[i], b[j], acc[i][j]);
        }
    }

#pragma unroll
    for (int i = 0; i < 4; ++i)
#pragma unroll
        for (int j = 0; j < 4; ++j) {
#pragma unroll
            for (int r = 0; r < 4; ++r) {
                const long gm = tileM + wm + i * 16 + kq * 4 + r;
                const long gn = tileN + wn + j * 16 + c15;
                const float v = acc[i][j][r];
                if (EPI == 0) {
                    ((bf16*)Cout)[gm * N + gn] = (bf16)v;
                } else if (EPI == 1) {
                    ((float*)Cout)[gm * N + gn] = v + bias[gn] + resid[gm * N + gn];
                } else {
                    ((bf16*)Cout)[gm * N + gn] = (bf16)gelu_fast(v + bias[gn]);
                }
            }
        }
}

// ---------------------------------------------------------------------------
// 256x256-tile bf16 NT GEMM, 8-phase schedule (T3+T4+T5), pinned skeleton.
// Measured R1/R2: ~parity with gemm_bt at K=1024 shapes. Kept for qkv/fc1.
// EPI: 2 = +bias,GELU -> bf16; 3 = qkv: Q/K bf16, V (n>=2048) transposed.
// ---------------------------------------------------------------------------
template <int EPI>
__global__ __launch_bounds__(512, 2)
void gemm_bt256(const bf16* __restrict__ A, const bf16* __restrict__ B,
                const float* __restrict__ bias, const float* __restrict__ resid,
                void* __restrict__ Cout, bf16* __restrict__ vtout,
                int M, int N, int K) {
    __shared__ __align__(16) bf16 s[4][2][8192];  // [H: A0,A1,B0,B1][buf][128x64]
    const int tid  = threadIdx.x;
    const int lane = tid & 63;
    const int wave = tid >> 6;
    const int c15 = lane & 15;
    const int kq  = lane >> 4;
    const int c7  = lane & 7;
    const int hA   = wave >> 2;          // which A half this wave reads
    const int hB   = (wave >> 1) & 1;    // which B half
    const int wsub = (wave & 1) << 6;    // col offset within B half
    const int wm = hA << 7;
    const int wn = (hB << 7) | wsub;
    const long tileM = (long)blockIdx.y * 256;
    const long tileN = (long)blockIdx.x * 256;
    const int nk = K >> 6;

    floatx4 acc[8][4] = {};

    const int srow = tid >> 3;                       // 0..63
    const int scol = ((tid & 7) ^ (srow & 7)) << 3;
    const bf16* ga0 = A + (tileM + srow) * (long)K + scol;
    const bf16* ga1 = ga0 + 128 * (long)K;
    const bf16* gb0 = B + (tileN + srow) * (long)K + scol;
    const bf16* gb1 = gb0 + 128 * (long)K;

#define STAGE(H, GP, kt)                                          \
    do {                                                          \
        if ((kt) < nk) {                                          \
            const bf16* _g = (GP) + ((long)(kt) << 6);            \
            bf16* _d = &s[H][(kt) & 1][tid * 8];                  \
            async_load16(_g, _d);                                 \
            async_load16(_g + 64 * (long)K, _d + 4096);           \
        }                                                         \
    } while (0)

// phase skeleton pins
#define PH_OPEN()                                                  \
    __builtin_amdgcn_sched_barrier(0);                             \
    __builtin_amdgcn_s_barrier();                                  \
    asm volatile("s_waitcnt lgkmcnt(0)" ::: "memory");             \
    __builtin_amdgcn_sched_barrier(0);                             \
    __builtin_amdgcn_s_setprio(1)

#define PH_CLOSE()                                                 \
    __builtin_amdgcn_s_setprio(0);                                 \
    __builtin_amdgcn_sched_barrier(0);                             \
    __builtin_amdgcn_s_barrier();                                  \
    __builtin_amdgcn_sched_barrier(0)

    // prologue: B0(0) B1(0) A0(0) A1(0) B0(1) B1(1); vmcnt(4) -> tile0 ready
    STAGE(2, gb0, 0); STAGE(3, gb1, 0);
    STAGE(0, ga0, 0); STAGE(1, ga1, 0);
    STAGE(2, gb0, 1); STAGE(3, gb1, 1);
    asm volatile("s_waitcnt vmcnt(4)" ::: "memory");
    __builtin_amdgcn_s_barrier();
    __builtin_amdgcn_sched_barrier(0);

    bf16x8 af[4][2], bL[2][2], bH[2][2];

#define RD(P, r, ks) \
    (*(const bf16x8*)((P) + ((r) << 6) + (((((ks) << 2) | kq) ^ c7) << 3)))

    for (int t = 0; t < nk; ++t) {
        const bf16* pa = s[hA][t & 1];
        const bf16* pb = s[2 + hB][t & 1];

        // ---- phase 1: quad (0,0) -------------------------------------
#pragma unroll
        for (int i = 0; i < 4; ++i) {
            af[i][0] = RD(pa, i * 16 + c15, 0);
            af[i][1] = RD(pa, i * 16 + c15, 1);
        }
#pragma unroll
        for (int j = 0; j < 2; ++j) {
            bL[j][0] = RD(pb, wsub + j * 16 + c15, 0);
            bL[j][1] = RD(pb, wsub + j * 16 + c15, 1);
        }
        STAGE(0, ga0, t + 1);
        PH_OPEN();
#pragma unroll
        for (int i = 0; i < 4; ++i)
#pragma unroll
            for (int j = 0; j < 2; ++j) {
                acc[i][j] = MFMA(af[i][0], bL[j][0], acc[i][j]);
                acc[i][j] = MFMA(af[i][1], bL[j][1], acc[i][j]);
            }
        PH_CLOSE();

        // ---- phase 2: quad (0,1) -------------------------------------
#pragma unroll
        for (int j = 0; j < 2; ++j) {
            bH[j][0] = RD(pb, wsub + 32 + j * 16 + c15, 0);
            bH[j][1] = RD(pb, wsub + 32 + j * 16 + c15, 1);
        }
        STAGE(1, ga1, t + 1);
        PH_OPEN();
#pragma unroll
        for (int i = 0; i < 4; ++i)
#pragma unroll
            for (int j = 0; j < 2; ++j) {
                acc[i][2 + j] = MFMA(af[i][0], bH[j][0], acc[i][2 + j]);
                acc[i][2 + j] = MFMA(af[i][1], bH[j][1], acc[i][2 + j]);
            }
        PH_CLOSE();

        // ---- phase 3: quad (1,1) -------------------------------------
#pragma unroll
        for (int i = 0; i < 4; ++i) {
            af[i][0] = RD(pa, 64 + i * 16 + c15, 0);
            af[i][1] = RD(pa, 64 + i * 16 + c15, 1);
        }
        STAGE(2, gb0, t + 2);
        PH_OPEN();
#pragma unroll
        for (int i = 0; i < 4; ++i)
#pragma unroll
            for (int j = 0; j < 2; ++j) {
                acc[4 + i][2 + j] = MFMA(af[i][0], bH[j][0], acc[4 + i][2 + j]);
                acc[4 + i][2 + j] = MFMA(af[i][1], bH[j][1], acc[4 + i][2 + j]);
            }
        PH_CLOSE();

        // ---- phase 4: quad (1,0), counted vmcnt at K-tile boundary ----
        STAGE(3, gb1, t + 2);
        __builtin_amdgcn_sched_barrier(0);
        __builtin_amdgcn_s_barrier();
        asm volatile("s_waitcnt lgkmcnt(0)" ::: "memory");
        __builtin_amdgcn_sched_barrier(0);
        __builtin_amdgcn_s_setprio(1);
#pragma unroll
        for (int i = 0; i < 4; ++i)
#pragma unroll
            for (int j = 0; j < 2; ++j) {
                acc[4 + i][j] = MFMA(af[i][0], bL[j][0], acc[4 + i][j]);
                acc[4 + i][j] = MFMA(af[i][1], bL[j][1], acc[4 + i][j]);
            }
        __builtin_amdgcn_s_setprio(0);
        __builtin_amdgcn_sched_barrier(0);
        asm volatile("s_waitcnt vmcnt(4)" ::: "memory");
        __builtin_amdgcn_s_barrier();
        __builtin_amdgcn_sched_barrier(0);
    }
#undef STAGE
#undef RD
#undef PH_OPEN
#undef PH_CLOSE

    // epilogue
#pragma unroll
    for (int i = 0; i < 8; ++i)
#pragma unroll
        for (int j = 0; j < 4; ++j) {
            if (EPI == 3 && tileN >= 2048) {
                // V: transposed store. Lane holds 4 consecutive tokens.
                const long gnv  = tileN - 2048 + wn + j * 16 + c15;
                const long tokb = tileM + wm + i * 16 + kq * 4;
                const long row  = ((tokb >> 11) << 10) + gnv;
                bf16x4 ov;
#pragma unroll
                for (int r = 0; r < 4; ++r) ov[r] = (bf16)acc[i][j][r];
                *(bf16x4*)(vtout + row * 2048 + (tokb & 2047)) = ov;
            } else {
#pragma unroll
                for (int r = 0; r < 4; ++r) {
                    const long gm = tileM + wm + i * 16 + kq * 4 + r;
                    const long gn = tileN + wn + j * 16 + c15;
                    const float v = acc[i][j][r];
                    if (EPI == 0 || EPI == 3) {
                        ((bf16*)Cout)[gm * N + gn] = (bf16)v;
                    } else if (EPI == 1) {
                        ((float*)Cout)[gm * N + gn] = v + bias[gn] + resid[gm * N + gn];
                    } else {
                        ((bf16*)Cout)[gm * N + gn] = (bf16)gelu_fast(v + bias[gn]);
                    }
                }
            }
        }
}

// ---------------------------------------------------------------------------
// Flash attention v9 = R4 structure (best measured: 88.6us) with ONE change:
// sP stride 72 -> 76 elements. Old stride: 36 dwords => c15*36 = c15*4 mod 32
// -> only 8 distinct banks across the 16 q-columns (4-way read conflicts;
// 6.29M conflict-cycles = ~384cy/block-iter, ~19% of the iteration). New
// stride 38 dwords: 6*c15 mod 32 injective on [0,16) -> all 16 q-columns on
// distinct banks; writes <=2-way (free, m136). LDS 53.2->55.3KB, still
// 2 blocks/CU. R8 lesson kept: q-block stays 256 (smaller blocks duplicate
// per-iter fixed costs). R5/R6 lesson kept: no min-waves hint > 2.
// ---------------------------------------------------------------------------
__global__ __launch_bounds__(256, 2)
void attn_kernel(const bf16* __restrict__ qkv, const bf16* __restrict__ vt,
                 bf16* __restrict__ o) {
    __shared__ __align__(16) bf16 sK[2][64 * 64];
    __shared__ __align__(16) bf16 sP[16][16 * 76];   // [wave*4+t][q][kv(+pad4)]
    const int bh = blockIdx.x, b = bh >> 4, h = bh & 15;
    const int q0 = blockIdx.y * 256;
    const int tid = threadIdx.x, lane = tid & 63, wave = tid >> 6;
    const int c15 = lane & 15, kq = lane >> 4, c7 = lane & 7;

    // Q fragments: 4 q-tiles of 16 rows per wave; pre-scaled by log2(e)/8
    bf16x8 qf[4][2];
#pragma unroll
    for (int t = 0; t < 4; ++t) {
        const bf16* qrow =
            qkv + ((long)(b * 2048 + q0 + wave * 64 + t * 16 + c15)) * 3072 + h * 64;
#pragma unroll
        for (int kk = 0; kk < 2; ++kk) {
            const bf16x8 raw = *(const bf16x8*)(qrow + kk * 32 + kq * 8);
            bf16x8 sc;
#pragma unroll
            for (int e = 0; e < 8; ++e) sc[e] = (bf16)((float)raw[e] * 0.18033688f);
            qf[t][kk] = sc;
        }
    }

    floatx4 oacc[4][4] = {};
    float l_s[4] = {0.f, 0.f, 0.f, 0.f};

    const bf16* kbase = qkv + ((long)b * 2048) * 3072 + 1024 + h * 64;
    const bf16* vbase = vt + (long)bh * 64 * 2048;

    const int srow = tid >> 3;
    const int scol = ((tid & 7) ^ (srow & 7)) * 8;
    bf16* sKw0 = &sK[0][tid * 8];
    bf16* sKw1 = &sK[1][tid * 8];

    // prologue: stage K tile 0 into buf 0
    async_load16(kbase + (long)(srow) * 3072 + scol, sKw0);
    async_load16(kbase + (long)(32 + srow) * 3072 + scol, sKw0 + 2048);
    __syncthreads();

    for (int it = 0; it < 32; ++it) {
        const int kv0 = it << 6;
        const int cur = it & 1;
        // stage next K tile into other buffer (hidden under this iter's compute)
        if (it + 1 < 32) {
            bf16* dst = cur ? sKw0 : sKw1;
            async_load16(kbase + (long)(kv0 + 64 + srow) * 3072 + scol, dst);
            async_load16(kbase + (long)(kv0 + 96 + srow) * 3072 + scol, dst + 2048);
        }

        // V^T fragments straight from global (L2-resident), issued early so
        // latency hides under S^T + softmax.
        bf16x8 vf[4][2];
#pragma unroll
        for (int i = 0; i < 4; ++i) {
            const bf16* vrow = vbase + (long)(i * 16 + c15) * 2048 + kv0 + kq * 8;
            vf[i][0] = *(const bf16x8*)(vrow);
            vf[i][1] = *(const bf16x8*)(vrow + 32);
        }

        // K fragments from LDS (swizzled)
        const bf16* sKr = cur ? sK[1] : sK[0];
        bf16x8 kf[4][2];
#pragma unroll
        for (int j = 0; j < 4; ++j) {
            kf[j][0] = *(const bf16x8*)(sKr + (j * 16 + c15) * 64 + ((kq ^ c7) * 8));
            kf[j][1] = *(const bf16x8*)(sKr + (j * 16 + c15) * 64 + (((4 | kq) ^ c7) * 8));
        }

        // S^T per q-tile, exp2, write P^T rows
#pragma unroll
        for (int t = 0; t < 4; ++t) {
            floatx4 sv[4];
#pragma unroll
            for (int j = 0; j < 4; ++j) {
                floatx4 a = {0.f, 0.f, 0.f, 0.f};
                a = MFMA(kf[j][0], qf[t][0], a);
                a = MFMA(kf[j][1], qf[t][1], a);
                sv[j] = a;
            }
            bf16* sPt = sP[wave * 4 + t];
            float rs = 0.f;
#pragma unroll
            for (int j = 0; j < 4; ++j) {
                const float p0 = __builtin_amdgcn_exp2f(sv[j][0]);
                const float p1 = __builtin_amdgcn_exp2f(sv[j][1]);
                const float p2 = __builtin_amdgcn_exp2f(sv[j][2]);
                const float p3 = __builtin_amdgcn_exp2f(sv[j][3]);
                rs += (p0 + p1) + (p2 + p3);
                bf16x4 pk;
                pk[0] = (bf16)p0; pk[1] = (bf16)p1; pk[2] = (bf16)p2; pk[3] = (bf16)p3;
                *(bf16x4*)(sPt + c15 * 76 + j * 16 + kq * 4) = pk;
            }
            l_s[t] += rs;
        }

        // PV: per q-tile read P^T fragment, 8 MFMA into O^T
#pragma unroll
        for (int t = 0; t < 4; ++t) {
            const bf16* sPt = sP[wave * 4 + t];
            const bf16x8 pf0 = *(const bf16x8*)(sPt + c15 * 76 + kq * 8);
            const bf16x8 pf1 = *(const bf16x8*)(sPt + c15 * 76 + 32 + kq * 8);
#pragma unroll
            for (int i = 0; i < 4; ++i) {
                oacc[t][i] = MFMA(vf[i][0], pf0, oacc[t][i]);
                oacc[t][i] = MFMA(vf[i][1], pf1, oacc[t][i]);
            }
        }

        __syncthreads();  // drains stage (hidden) + protects sK[cur] reuse
    }

    // final cross-lane denom reduction + O write
#pragma unroll
    for (int t = 0; t < 4; ++t) {
        float rs = l_s[t];
        rs += __shfl_xor(rs, 16, 64);
        rs += __shfl_xor(rs, 32, 64);
        const float linv = 1.0f / rs;
        const long tok = (long)(b * 2048 + q0 + wave * 64 + t * 16 + c15);
#pragma unroll
        for (int i = 0; i < 4; ++i) {
            bf16x4 ov;
#pragma unroll
            for (int r = 0; r < 4; ++r) ov[r] = (bf16)(oacc[t][i][r] * linv);
            *(bf16x4*)(o + tok * 1024 + h * 64 + i * 16 + kq * 4) = ov;
        }
    }
}

// ---------------------------------------------------------------------------
extern "C" void kernel_launch(void* const* d_in, const int* in_sizes, int n_in,
                              void* d_out, int out_size, void* d_ws, size_t ws_size,
                              hipStream_t stream) {
    const float* x      = (const float*)d_in[0];
    const float* ln1_g  = (const float*)d_in[1];
    const float* ln1_b  = (const float*)d_in[2];
    const float* qkv_w  = (const float*)d_in[3];
    const float* proj_w = (const float*)d_in[4];
    const float* proj_b = (const float*)d_in[5];
    const float* ln2_g  = (const float*)d_in[6];
    const float* ln2_b  = (const float*)d_in[7];
    const float* fc1_w  = (const float*)d_in[8];
    const float* fc1_b  = (const float*)d_in[9];
    const float* fc2_w  = (const float*)d_in[10];
    const float* fc2_b  = (const float*)d_in[11];
    float* out = (float*)d_out;

    char* ws = (char*)d_ws;
    bf16* actbuf = (bf16*)(ws);                            // 16 MiB (h / o / h2)
    bf16* wqkv   = (bf16*)(ws + (16ull << 20));            // 6 MiB
    bf16* wproj  = (bf16*)(ws + (22ull << 20));            // 2 MiB
    bf16* wfc1   = (bf16*)(ws + (24ull << 20));            // 8 MiB
    bf16* wfc2   = (bf16*)(ws + (32ull << 20));            // 8 MiB
    bf16* qkvbuf = (bf16*)(ws + (40ull << 20));            // 48 MiB (V region unused)
    bf16* vtbuf  = (bf16*)(ws + (88ull << 20));            // 16 MiB
    bf16* gbuf   = (bf16*)(ws + (40ull << 20));            // 64 MiB (aliases qkv+vt)

    const dim3 blk(256);
    const dim3 blk512(512);

    cast4_kernel<<<6144, blk, 0, stream>>>(qkv_w, proj_w, fc1_w, fc2_w,
                                           wqkv, wproj, wfc1, wfc2);

    ln_kernel<<<8192, blk, 0, stream>>>(x, ln1_g, ln1_b, actbuf);

    gemm_bt256<3><<<dim3(12, 32), blk512, 0, stream>>>(actbuf, wqkv, nullptr, nullptr,
                                                       qkvbuf, vtbuf, 8192, 3072, 1024);
    attn_kernel<<<dim3(64, 8), blk, 0, stream>>>(qkvbuf, vtbuf, actbuf);

    gemm_bt<1><<<dim3(8, 64), blk, 0, stream>>>(actbuf, wproj, proj_b, x,
                                                d_out, nullptr, 8192, 1024, 1024);

    ln_kernel<<<8192, blk, 0, stream>>>(out, ln2_g, ln2_b, actbuf);

    gemm_bt256<2><<<dim3(16, 32), blk512, 0, stream>>>(actbuf, wfc1, fc1_b, nullptr,
                                                       gbuf, nullptr, 8192, 4096, 1024);
    gemm_bt<1><<<dim3(8, 64), blk, 0, stream>>>(gbuf, wfc2, fc2_b, out,
                                                d_out, nullptr, 8192, 1024, 4096);
}

// Round 10
// 472.693 us; speedup vs baseline: 1.1786x; 1.1170x over previous
//
#include <hip/hip_runtime.h>
#include <math.h>

typedef __bf16 bf16;
typedef __attribute__((ext_vector_type(8))) __bf16 bf16x8;
typedef __attribute__((ext_vector_type(4))) __bf16 bf16x4;
typedef __attribute__((ext_vector_type(4))) float floatx4;

#define MFMA(a, b, c) __builtin_amdgcn_mfma_f32_16x16x32_bf16((a), (b), (c), 0, 0, 0)

__device__ __forceinline__ void async_load16(const bf16* g, bf16* l) {
    __builtin_amdgcn_global_load_lds((const __attribute__((address_space(1))) void*)(g),
                                     (__attribute__((address_space(3))) void*)(l), 16, 0, 0);
}

// fast GELU (tanh form, exp2-based). |diff vs exact erf-gelu| <= ~3e-3.
__device__ __forceinline__ float gelu_fast(float t) {
    const float g  = 0.7978845608f * (t + 0.044715f * t * t * t);
    const float u  = __builtin_amdgcn_exp2f(g * 2.885390082f);  // e^{2g}
    const float th = (u - 1.0f) * __builtin_amdgcn_rcpf(u + 1.0f);
    return 0.5f * t * (1.0f + th);
}

// XCD-aware bijective block swizzle (T1, m157/m204). HW round-robins linear
// block id n across 8 XCDs (XCD = n%8); remapping tile = (n%8)*(nwg/8)+n/8
// gives each XCD a CONTIGUOUS run of tiles -> A-panels and B-panels become
// XCD-L2-resident. Valid iff nwg%8==0 (all our GEMM grids: 384/512/2048/512).
__device__ __forceinline__ void xcd_swizzle(int& bx, int& by) {
    const int gx  = gridDim.x;
    const int nwg = gx * gridDim.y;
    const int n   = bx + gx * by;
    const int swz = (n & 7) * (nwg >> 3) + (n >> 3);
    bx = swz % gx;
    by = swz / gx;
}

// ---------------------------------------------------------------------------
// fp32 -> bf16 cast of all 4 weight matrices in one launch.
// ---------------------------------------------------------------------------
__global__ __launch_bounds__(256) void cast4_kernel(const float* __restrict__ a0,
                                                    const float* __restrict__ a1,
                                                    const float* __restrict__ a2,
                                                    const float* __restrict__ a3,
                                                    bf16* __restrict__ o0,
                                                    bf16* __restrict__ o1,
                                                    bf16* __restrict__ o2,
                                                    bf16* __restrict__ o3) {
    long i = (long)blockIdx.x * 256 + threadIdx.x;  // 8-elem units
    const float* in;
    bf16* out;
    long off;
    if (i < 393216) { in = a0; out = o0; off = i; }
    else if (i < 524288) { in = a1; out = o1; off = i - 393216; }
    else if (i < 1048576) { in = a2; out = o2; off = i - 524288; }
    else { in = a3; out = o3; off = i - 1048576; }
    const float4 a = ((const float4*)in)[2 * off];
    const float4 b = ((const float4*)in)[2 * off + 1];
    bf16x8 o;
    o[0] = (bf16)a.x; o[1] = (bf16)a.y; o[2] = (bf16)a.z; o[3] = (bf16)a.w;
    o[4] = (bf16)b.x; o[5] = (bf16)b.y; o[6] = (bf16)b.z; o[7] = (bf16)b.w;
    *(bf16x8*)(out + off * 8) = o;
}

// ---------------------------------------------------------------------------
// LayerNorm over 1024 cols, fp32 in -> bf16 out. One block (256 thr) per row.
// ---------------------------------------------------------------------------
__global__ __launch_bounds__(256) void ln_kernel(const float* __restrict__ x,
                                                 const float* __restrict__ g,
                                                 const float* __restrict__ b,
                                                 bf16* __restrict__ out) {
    const int row = blockIdx.x;
    const int tid = threadIdx.x;
    const float4 v = ((const float4*)(x + (long)row * 1024))[tid];
    float s  = v.x + v.y + v.z + v.w;
    float s2 = v.x * v.x + v.y * v.y + v.z * v.z + v.w * v.w;
#pragma unroll
    for (int off = 32; off > 0; off >>= 1) {
        s  += __shfl_xor(s, off, 64);
        s2 += __shfl_xor(s2, off, 64);
    }
    __shared__ float red[8];
    const int wave = tid >> 6, lane = tid & 63;
    if (lane == 0) { red[wave] = s; red[wave + 4] = s2; }
    __syncthreads();
    const float ts  = red[0] + red[1] + red[2] + red[3];
    const float ts2 = red[4] + red[5] + red[6] + red[7];
    const float mu   = ts * (1.0f / 1024.0f);
    const float rstd = rsqrtf(ts2 * (1.0f / 1024.0f) - mu * mu + 1e-5f);
    const float4 gg = ((const float4*)g)[tid];
    const float4 bb = ((const float4*)b)[tid];
    bf16x4 o;
    o[0] = (bf16)((v.x - mu) * rstd * gg.x + bb.x);
    o[1] = (bf16)((v.y - mu) * rstd * gg.y + bb.y);
    o[2] = (bf16)((v.z - mu) * rstd * gg.z + bb.z);
    o[3] = (bf16)((v.w - mu) * rstd * gg.w + bb.w);
    *(bf16x4*)(out + (long)row * 1024 + tid * 4) = o;
}

// ---------------------------------------------------------------------------
// 128x128-tile bf16 NT GEMM (m97 structure) + XCD swizzle (T1).
// Kept for N=1024 GEMMs (proj, fc2). EPI: 1 = +bias+resid -> fp32 out.
// ---------------------------------------------------------------------------
template <int EPI>
__global__ __launch_bounds__(256, 4)
void gemm_bt(const bf16* __restrict__ A, const bf16* __restrict__ B,
             const float* __restrict__ bias, const float* __restrict__ resid,
             void* __restrict__ Cout, bf16* __restrict__ vtout, int M, int N, int K) {
    __shared__ __align__(16) bf16 sA[128 * 64];
    __shared__ __align__(16) bf16 sB[128 * 64];
    const int tid  = threadIdx.x;
    const int lane = tid & 63;
    const int wave = tid >> 6;
    const int wm = (wave >> 1) << 6;
    const int wn = (wave & 1) << 6;
    const int c15 = lane & 15;
    const int kq  = lane >> 4;
    const int c7  = lane & 7;
    int bx = blockIdx.x, by = blockIdx.y;
    xcd_swizzle(bx, by);
    const long tileM = (long)by * 128;
    const long tileN = (long)bx * 128;

    floatx4 acc[4][4] = {};

    const int srow = tid >> 3;
    const int scol = ((tid & 7) ^ (srow & 7)) * 8;
    const bf16* Abase = A + (tileM + srow) * (long)K + scol;
    const bf16* Bbase = B + (tileN + srow) * (long)K + scol;
    bf16* sAw = sA + tid * 8;
    bf16* sBw = sB + tid * 8;

    for (int k0 = 0; k0 < K; k0 += 64) {
        __syncthreads();
#pragma unroll
        for (int it = 0; it < 4; ++it) {
            async_load16(Abase + (long)it * 32 * K + k0, sAw + it * 2048);
            async_load16(Bbase + (long)it * 32 * K + k0, sBw + it * 2048);
        }
        __syncthreads();
#pragma unroll
        for (int kk = 0; kk < 2; ++kk) {
            bf16x8 a[4], b[4];
#pragma unroll
            for (int i = 0; i < 4; ++i) {
                const int ch = ((kk << 2) + kq) ^ c7;
                a[i] = *(const bf16x8*)(sA + (wm + i * 16 + c15) * 64 + ch * 8);
                b[i] = *(const bf16x8*)(sB + (wn + i * 16 + c15) * 64 + ch * 8);
            }
#pragma unroll
            for (int i = 0; i < 4; ++i)
#pragma unroll
                for (int j = 0; j < 4; ++j)
                    acc[i][j] = MFMA(a[i], b[j], acc[i][j]);
        }
    }

#pragma unroll
    for (int i = 0; i < 4; ++i)
#pragma unroll
        for (int j = 0; j < 4; ++j) {
#pragma unroll
            for (int r = 0; r < 4; ++r) {
                const long gm = tileM + wm + i * 16 + kq * 4 + r;
                const long gn = tileN + wn + j * 16 + c15;
                const float v = acc[i][j][r];
                if (EPI == 0) {
                    ((bf16*)Cout)[gm * N + gn] = (bf16)v;
                } else if (EPI == 1) {
                    ((float*)Cout)[gm * N + gn] = v + bias[gn] + resid[gm * N + gn];
                } else {
                    ((bf16*)Cout)[gm * N + gn] = (bf16)gelu_fast(v + bias[gn]);
                }
            }
        }
}

// ---------------------------------------------------------------------------
// 256x256-tile bf16 NT GEMM, 8-phase schedule (T3+T4+T5), pinned skeleton,
// + XCD swizzle (T1). Kept for qkv/fc1.
// EPI: 2 = +bias,GELU -> bf16; 3 = qkv: Q/K bf16, V (n>=2048) transposed.
// ---------------------------------------------------------------------------
template <int EPI>
__global__ __launch_bounds__(512, 2)
void gemm_bt256(const bf16* __restrict__ A, const bf16* __restrict__ B,
                const float* __restrict__ bias, const float* __restrict__ resid,
                void* __restrict__ Cout, bf16* __restrict__ vtout,
                int M, int N, int K) {
    __shared__ __align__(16) bf16 s[4][2][8192];  // [H: A0,A1,B0,B1][buf][128x64]
    const int tid  = threadIdx.x;
    const int lane = tid & 63;
    const int wave = tid >> 6;
    const int c15 = lane & 15;
    const int kq  = lane >> 4;
    const int c7  = lane & 7;
    const int hA   = wave >> 2;          // which A half this wave reads
    const int hB   = (wave >> 1) & 1;    // which B half
    const int wsub = (wave & 1) << 6;    // col offset within B half
    const int wm = hA << 7;
    const int wn = (hB << 7) | wsub;
    int bx = blockIdx.x, by = blockIdx.y;
    xcd_swizzle(bx, by);
    const long tileM = (long)by * 256;
    const long tileN = (long)bx * 256;
    const int nk = K >> 6;

    floatx4 acc[8][4] = {};

    const int srow = tid >> 3;                       // 0..63
    const int scol = ((tid & 7) ^ (srow & 7)) << 3;
    const bf16* ga0 = A + (tileM + srow) * (long)K + scol;
    const bf16* ga1 = ga0 + 128 * (long)K;
    const bf16* gb0 = B + (tileN + srow) * (long)K + scol;
    const bf16* gb1 = gb0 + 128 * (long)K;

#define STAGE(H, GP, kt)                                          \
    do {                                                          \
        if ((kt) < nk) {                                          \
            const bf16* _g = (GP) + ((long)(kt) << 6);            \
            bf16* _d = &s[H][(kt) & 1][tid * 8];                  \
            async_load16(_g, _d);                                 \
            async_load16(_g + 64 * (long)K, _d + 4096);           \
        }                                                         \
    } while (0)

// phase skeleton pins
#define PH_OPEN()                                                  \
    __builtin_amdgcn_sched_barrier(0);                             \
    __builtin_amdgcn_s_barrier();                                  \
    asm volatile("s_waitcnt lgkmcnt(0)" ::: "memory");             \
    __builtin_amdgcn_sched_barrier(0);                             \
    __builtin_amdgcn_s_setprio(1)

#define PH_CLOSE()                                                 \
    __builtin_amdgcn_s_setprio(0);                                 \
    __builtin_amdgcn_sched_barrier(0);                             \
    __builtin_amdgcn_s_barrier();                                  \
    __builtin_amdgcn_sched_barrier(0)

    // prologue: B0(0) B1(0) A0(0) A1(0) B0(1) B1(1); vmcnt(4) -> tile0 ready
    STAGE(2, gb0, 0); STAGE(3, gb1, 0);
    STAGE(0, ga0, 0); STAGE(1, ga1, 0);
    STAGE(2, gb0, 1); STAGE(3, gb1, 1);
    asm volatile("s_waitcnt vmcnt(4)" ::: "memory");
    __builtin_amdgcn_s_barrier();
    __builtin_amdgcn_sched_barrier(0);

    bf16x8 af[4][2], bL[2][2], bH[2][2];

#define RD(P, r, ks) \
    (*(const bf16x8*)((P) + ((r) << 6) + (((((ks) << 2) | kq) ^ c7) << 3)))

    for (int t = 0; t < nk; ++t) {
        const bf16* pa = s[hA][t & 1];
        const bf16* pb = s[2 + hB][t & 1];

        // ---- phase 1: quad (0,0) -------------------------------------
#pragma unroll
        for (int i = 0; i < 4; ++i) {
            af[i][0] = RD(pa, i * 16 + c15, 0);
            af[i][1] = RD(pa, i * 16 + c15, 1);
        }
#pragma unroll
        for (int j = 0; j < 2; ++j) {
            bL[j][0] = RD(pb, wsub + j * 16 + c15, 0);
            bL[j][1] = RD(pb, wsub + j * 16 + c15, 1);
        }
        STAGE(0, ga0, t + 1);
        PH_OPEN();
#pragma unroll
        for (int i = 0; i < 4; ++i)
#pragma unroll
            for (int j = 0; j < 2; ++j) {
                acc[i][j] = MFMA(af[i][0], bL[j][0], acc[i][j]);
                acc[i][j] = MFMA(af[i][1], bL[j][1], acc[i][j]);
            }
        PH_CLOSE();

        // ---- phase 2: quad (0,1) -------------------------------------
#pragma unroll
        for (int j = 0; j < 2; ++j) {
            bH[j][0] = RD(pb, wsub + 32 + j * 16 + c15, 0);
            bH[j][1] = RD(pb, wsub + 32 + j * 16 + c15, 1);
        }
        STAGE(1, ga1, t + 1);
        PH_OPEN();
#pragma unroll
        for (int i = 0; i < 4; ++i)
#pragma unroll
            for (int j = 0; j < 2; ++j) {
                acc[i][2 + j] = MFMA(af[i][0], bH[j][0], acc[i][2 + j]);
                acc[i][2 + j] = MFMA(af[i][1], bH[j][1], acc[i][2 + j]);
            }
        PH_CLOSE();

        // ---- phase 3: quad (1,1) -------------------------------------
#pragma unroll
        for (int i = 0; i < 4; ++i) {
            af[i][0] = RD(pa, 64 + i * 16 + c15, 0);
            af[i][1] = RD(pa, 64 + i * 16 + c15, 1);
        }
        STAGE(2, gb0, t + 2);
        PH_OPEN();
#pragma unroll
        for (int i = 0; i < 4; ++i)
#pragma unroll
            for (int j = 0; j < 2; ++j) {
                acc[4 + i][2 + j] = MFMA(af[i][0], bH[j][0], acc[4 + i][2 + j]);
                acc[4 + i][2 + j] = MFMA(af[i][1], bH[j][1], acc[4 + i][2 + j]);
            }
        PH_CLOSE();

        // ---- phase 4: quad (1,0), counted vmcnt at K-tile boundary ----
        STAGE(3, gb1, t + 2);
        __builtin_amdgcn_sched_barrier(0);
        __builtin_amdgcn_s_barrier();
        asm volatile("s_waitcnt lgkmcnt(0)" ::: "memory");
        __builtin_amdgcn_sched_barrier(0);
        __builtin_amdgcn_s_setprio(1);
#pragma unroll
        for (int i = 0; i < 4; ++i)
#pragma unroll
            for (int j = 0; j < 2; ++j) {
                acc[4 + i][j] = MFMA(af[i][0], bL[j][0], acc[4 + i][j]);
                acc[4 + i][j] = MFMA(af[i][1], bL[j][1], acc[4 + i][j]);
            }
        __builtin_amdgcn_s_setprio(0);
        __builtin_amdgcn_sched_barrier(0);
        asm volatile("s_waitcnt vmcnt(4)" ::: "memory");
        __builtin_amdgcn_s_barrier();
        __builtin_amdgcn_sched_barrier(0);
    }
#undef STAGE
#undef RD
#undef PH_OPEN
#undef PH_CLOSE

    // epilogue
#pragma unroll
    for (int i = 0; i < 8; ++i)
#pragma unroll
        for (int j = 0; j < 4; ++j) {
            if (EPI == 3 && tileN >= 2048) {
                // V: transposed store. Lane holds 4 consecutive tokens.
                const long gnv  = tileN - 2048 + wn + j * 16 + c15;
                const long tokb = tileM + wm + i * 16 + kq * 4;
                const long row  = ((tokb >> 11) << 10) + gnv;
                bf16x4 ov;
#pragma unroll
                for (int r = 0; r < 4; ++r) ov[r] = (bf16)acc[i][j][r];
                *(bf16x4*)(vtout + row * 2048 + (tokb & 2047)) = ov;
            } else {
#pragma unroll
                for (int r = 0; r < 4; ++r) {
                    const long gm = tileM + wm + i * 16 + kq * 4 + r;
                    const long gn = tileN + wn + j * 16 + c15;
                    const float v = acc[i][j][r];
                    if (EPI == 0 || EPI == 3) {
                        ((bf16*)Cout)[gm * N + gn] = (bf16)v;
                    } else if (EPI == 1) {
                        ((float*)Cout)[gm * N + gn] = v + bias[gn] + resid[gm * N + gn];
                    } else {
                        ((bf16*)Cout)[gm * N + gn] = (bf16)gelu_fast(v + bias[gn]);
                    }
                }
            }
        }
}

// ---------------------------------------------------------------------------
// Flash attention — EXACT R4 revert (best measured: 88.6us). R5-R9 lessons:
// occupancy hints clamp VGPR (64-step) and serialize; smaller q-blocks
// duplicate per-iter fixed costs; permlane-P puts pack on the critical path;
// sP padding can't fix 8-bank aliasing without breaking 16B alignment
// (R9: stride 76 -> unaligned b128, +43us). The 4-way sP conflict tax is
// partially hidden and NOT the critical path. attn grid needs no XCD swizzle:
// blocks sharing bh are congruent mod 8 -> already same XCD.
// ---------------------------------------------------------------------------
__global__ __launch_bounds__(256, 2)
void attn_kernel(const bf16* __restrict__ qkv, const bf16* __restrict__ vt,
                 bf16* __restrict__ o) {
    __shared__ __align__(16) bf16 sK[2][64 * 64];
    __shared__ __align__(16) bf16 sP[16][16 * 72];   // [wave*4+t][q][kv(+pad)]
    const int bh = blockIdx.x, b = bh >> 4, h = bh & 15;
    const int q0 = blockIdx.y * 256;
    const int tid = threadIdx.x, lane = tid & 63, wave = tid >> 6;
    const int c15 = lane & 15, kq = lane >> 4, c7 = lane & 7;

    // Q fragments: 4 q-tiles of 16 rows per wave; pre-scaled by log2(e)/8
    bf16x8 qf[4][2];
#pragma unroll
    for (int t = 0; t < 4; ++t) {
        const bf16* qrow =
            qkv + ((long)(b * 2048 + q0 + wave * 64 + t * 16 + c15)) * 3072 + h * 64;
#pragma unroll
        for (int kk = 0; kk < 2; ++kk) {
            const bf16x8 raw = *(const bf16x8*)(qrow + kk * 32 + kq * 8);
            bf16x8 sc;
#pragma unroll
            for (int e = 0; e < 8; ++e) sc[e] = (bf16)((float)raw[e] * 0.18033688f);
            qf[t][kk] = sc;
        }
    }

    floatx4 oacc[4][4] = {};
    float l_s[4] = {0.f, 0.f, 0.f, 0.f};

    const bf16* kbase = qkv + ((long)b * 2048) * 3072 + 1024 + h * 64;
    const bf16* vbase = vt + (long)bh * 64 * 2048;

    const int srow = tid >> 3;
    const int scol = ((tid & 7) ^ (srow & 7)) * 8;
    bf16* sKw0 = &sK[0][tid * 8];
    bf16* sKw1 = &sK[1][tid * 8];

    // prologue: stage K tile 0 into buf 0
    async_load16(kbase + (long)(srow) * 3072 + scol, sKw0);
    async_load16(kbase + (long)(32 + srow) * 3072 + scol, sKw0 + 2048);
    __syncthreads();

    for (int it = 0; it < 32; ++it) {
        const int kv0 = it << 6;
        const int cur = it & 1;
        // stage next K tile into other buffer (hidden under this iter's compute)
        if (it + 1 < 32) {
            bf16* dst = cur ? sKw0 : sKw1;
            async_load16(kbase + (long)(kv0 + 64 + srow) * 3072 + scol, dst);
            async_load16(kbase + (long)(kv0 + 96 + srow) * 3072 + scol, dst + 2048);
        }

        // V^T fragments straight from global (L2-resident), issued early so
        // latency hides under S^T + softmax.
        bf16x8 vf[4][2];
#pragma unroll
        for (int i = 0; i < 4; ++i) {
            const bf16* vrow = vbase + (long)(i * 16 + c15) * 2048 + kv0 + kq * 8;
            vf[i][0] = *(const bf16x8*)(vrow);
            vf[i][1] = *(const bf16x8*)(vrow + 32);
        }

        // K fragments from LDS (swizzled)
        const bf16* sKr = cur ? sK[1] : sK[0];
        bf16x8 kf[4][2];
#pragma unroll
        for (int j = 0; j < 4; ++j) {
            kf[j][0] = *(const bf16x8*)(sKr + (j * 16 + c15) * 64 + ((kq ^ c7) * 8));
            kf[j][1] = *(const bf16x8*)(sKr + (j * 16 + c15) * 64 + (((4 | kq) ^ c7) * 8));
        }

        // S^T per q-tile, exp2, write P^T rows
#pragma unroll
        for (int t = 0; t < 4; ++t) {
            floatx4 sv[4];
#pragma unroll
            for (int j = 0; j < 4; ++j) {
                floatx4 a = {0.f, 0.f, 0.f, 0.f};
                a = MFMA(kf[j][0], qf[t][0], a);
                a = MFMA(kf[j][1], qf[t][1], a);
                sv[j] = a;
            }
            bf16* sPt = sP[wave * 4 + t];
            float rs = 0.f;
#pragma unroll
            for (int j = 0; j < 4; ++j) {
                const float p0 = __builtin_amdgcn_exp2f(sv[j][0]);
                const float p1 = __builtin_amdgcn_exp2f(sv[j][1]);
                const float p2 = __builtin_amdgcn_exp2f(sv[j][2]);
                const float p3 = __builtin_amdgcn_exp2f(sv[j][3]);
                rs += (p0 + p1) + (p2 + p3);
                bf16x4 pk;
                pk[0] = (bf16)p0; pk[1] = (bf16)p1; pk[2] = (bf16)p2; pk[3] = (bf16)p3;
                *(bf16x4*)(sPt + c15 * 72 + j * 16 + kq * 4) = pk;
            }
            l_s[t] += rs;
        }

        // PV: per q-tile read P^T fragment, 8 MFMA into O^T
#pragma unroll
        for (int t = 0; t < 4; ++t) {
            const bf16* sPt = sP[wave * 4 + t];
            const bf16x8 pf0 = *(const bf16x8*)(sPt + c15 * 72 + kq * 8);
            const bf16x8 pf1 = *(const bf16x8*)(sPt + c15 * 72 + 32 + kq * 8);
#pragma unroll
            for (int i = 0; i < 4; ++i) {
                oacc[t][i] = MFMA(vf[i][0], pf0, oacc[t][i]);
                oacc[t][i] = MFMA(vf[i][1], pf1, oacc[t][i]);
            }
        }

        __syncthreads();  // drains stage (hidden) + protects sK[cur] reuse
    }

    // final cross-lane denom reduction + O write
#pragma unroll
    for (int t = 0; t < 4; ++t) {
        float rs = l_s[t];
        rs += __shfl_xor(rs, 16, 64);
        rs += __shfl_xor(rs, 32, 64);
        const float linv = 1.0f / rs;
        const long tok = (long)(b * 2048 + q0 + wave * 64 + t * 16 + c15);
#pragma unroll
        for (int i = 0; i < 4; ++i) {
            bf16x4 ov;
#pragma unroll
            for (int r = 0; r < 4; ++r) ov[r] = (bf16)(oacc[t][i][r] * linv);
            *(bf16x4*)(o + tok * 1024 + h * 64 + i * 16 + kq * 4) = ov;
        }
    }
}

// ---------------------------------------------------------------------------
extern "C" void kernel_launch(void* const* d_in, const int* in_sizes, int n_in,
                              void* d_out, int out_size, void* d_ws, size_t ws_size,
                              hipStream_t stream) {
    const float* x      = (const float*)d_in[0];
    const float* ln1_g  = (const float*)d_in[1];
    const float* ln1_b  = (const float*)d_in[2];
    const float* qkv_w  = (const float*)d_in[3];
    const float* proj_w = (const float*)d_in[4];
    const float* proj_b = (const float*)d_in[5];
    const float* ln2_g  = (const float*)d_in[6];
    const float* ln2_b  = (const float*)d_in[7];
    const float* fc1_w  = (const float*)d_in[8];
    const float* fc1_b  = (const float*)d_in[9];
    const float* fc2_w  = (const float*)d_in[10];
    const float* fc2_b  = (const float*)d_in[11];
    float* out = (float*)d_out;

    char* ws = (char*)d_ws;
    bf16* actbuf = (bf16*)(ws);                            // 16 MiB (h / o / h2)
    bf16* wqkv   = (bf16*)(ws + (16ull << 20));            // 6 MiB
    bf16* wproj  = (bf16*)(ws + (22ull << 20));            // 2 MiB
    bf16* wfc1   = (bf16*)(ws + (24ull << 20));            // 8 MiB
    bf16* wfc2   = (bf16*)(ws + (32ull << 20));            // 8 MiB
    bf16* qkvbuf = (bf16*)(ws + (40ull << 20));            // 48 MiB (V region unused)
    bf16* vtbuf  = (bf16*)(ws + (88ull << 20));            // 16 MiB
    bf16* gbuf   = (bf16*)(ws + (40ull << 20));            // 64 MiB (aliases qkv+vt)

    const dim3 blk(256);
    const dim3 blk512(512);

    cast4_kernel<<<6144, blk, 0, stream>>>(qkv_w, proj_w, fc1_w, fc2_w,
                                           wqkv, wproj, wfc1, wfc2);

    ln_kernel<<<8192, blk, 0, stream>>>(x, ln1_g, ln1_b, actbuf);

    gemm_bt256<3><<<dim3(12, 32), blk512, 0, stream>>>(actbuf, wqkv, nullptr, nullptr,
                                                       qkvbuf, vtbuf, 8192, 3072, 1024);
    attn_kernel<<<dim3(64, 8), blk, 0, stream>>>(qkvbuf, vtbuf, actbuf);

    gemm_bt<1><<<dim3(8, 64), blk, 0, stream>>>(actbuf, wproj, proj_b, x,
                                                d_out, nullptr, 8192, 1024, 1024);

    ln_kernel<<<8192, blk, 0, stream>>>(out, ln2_g, ln2_b, actbuf);

    gemm_bt256<2><<<dim3(16, 32), blk512, 0, stream>>>(actbuf, wfc1, fc1_b, nullptr,
                                                       gbuf, nullptr, 8192, 4096, 1024);
    gemm_bt<1><<<dim3(8, 64), blk, 0, stream>>>(gbuf, wfc2, fc2_b, out,
                                                d_out, nullptr, 8192, 1024, 4096);
}